// Round 3
// baseline (403.174 us; speedup 1.0000x reference)
//
#include <hip/hip_runtime.h>

// BlockMaskGenerator: B=8192, NUM_BLOCKS=4, H=W=64, S=4096.
// Outputs (int32, concatenated): context[B*S], target[B*S], positions[B*S], counts[B].
// positions[b] = stable partition: target indices ascending, then non-target ascending.
//
// One 256-thread block per batch row.
//  - thread owns 16 consecutive positions; wave-shuffle + LDS scan -> ranks.
//  - positions scattered into LDS with XOR bank swizzle (breaks the stride-16
//    pathology: raw scatter is ~8-32-way bank conflicted), branchless 1 write/k.
//  - gather back with swizzled scalar ds_reads (~2-way, free), store coalesced int4.
//  - masks stored with independent coalesced ownership (int4 at g*256+tid).

#define NBLK 4
#define HGT 64
#define WID 64
#define SEQ 4096

__device__ __forceinline__ int swz(int i) { return i ^ ((i >> 5) & 31); }

__global__ __launch_bounds__(256) void blockmask_kernel(
    const float* __restrict__ scales,
    const float* __restrict__ rand_tops,
    const float* __restrict__ rand_lefts,
    int* __restrict__ out,
    int B)
{
    __shared__ int pos_s[SEQ];   // 16 KB, XOR-swizzled layout
    __shared__ int wsum[4];

    const int b   = blockIdx.x;
    const int tid = threadIdx.x;

    // --- per-batch rectangles (redundant per thread; trivial) ---
    int top[NBLK], bot[NBLK], lft[NBLK], rgt[NBLK];
#pragma unroll
    for (int j = 0; j < NBLK; ++j) {
        int t = b * NBLK + j;
        float sc = scales[t];
        float s = __fadd_rn(0.15f, __fmul_rn(sc, 0.05f));           // no FMA contraction
        int area = (int)__fmul_rn(__fmul_rn(s, 64.0f), 64.0f);      // trunc
        int bh = (int)__fsqrt_rn((float)area);                       // IEEE sqrt, trunc
        bh = min(max(bh, 1), HGT);
        int bw = (int)__fdiv_rn((float)area, (float)bh);             // IEEE div, trunc
        bw = min(max(bw, 1), WID);
        int maxt = max(HGT - bh + 1, 1);
        int maxl = max(WID - bw + 1, 1);
        int tp = (int)__fmul_rn(rand_tops[t],  (float)maxt);
        int lf = (int)__fmul_rn(rand_lefts[t], (float)maxl);
        top[j] = tp; bot[j] = tp + bh;
        lft[j] = lf; rgt[j] = lf + bw;
    }

    // --- membership for owned strip: row r, cols [c0, c0+16) ---
    const int p0 = tid * 16;
    const int r  = p0 >> 6;
    const int c0 = p0 & 63;

    unsigned mask16 = 0;
#pragma unroll
    for (int j = 0; j < NBLK; ++j) {
        if (r >= top[j] && r < bot[j]) {
            int lo = max(lft[j] - c0, 0);
            int hi = min(rgt[j] - c0, 16);
            if (hi > lo) mask16 |= ((1u << (hi - lo)) - 1u) << lo;
        }
    }
    const int cnt = __popc(mask16);

    // --- block-wide inclusive scan over 256 threads (wave=64) ---
    const int lane = tid & 63;
    const int wv   = tid >> 6;
    int v = cnt;
#pragma unroll
    for (int d = 1; d < 64; d <<= 1) {
        int t = __shfl_up(v, d, 64);
        if (lane >= d) v += t;
    }
    if (lane == 63) wsum[wv] = v;
    __syncthreads();
    int waveOff = 0, total = 0;
#pragma unroll
    for (int w = 0; w < 4; ++w) {
        int ws = wsum[w];
        if (w < wv) waveOff += ws;
        total += ws;
    }
    const int base_t = waveOff + (v - cnt);   // # targets before p0
    const int bn0    = total + (p0 - base_t); // non-target base for this strip

    // --- branchless swizzled scatter: one ds_write per position ---
    int pc = 0;
#pragma unroll
    for (int k = 0; k < 16; ++k) {
        int bit = (int)((mask16 >> k) & 1u);
        int idx = bit ? (base_t + pc) : (bn0 + k - pc);
        pos_s[swz(idx)] = p0 + k;
        pc += bit;
    }

    // --- coalesced mask stores (int4 at g*256+tid) ---
    const size_t BS = (size_t)B * SEQ;
    int4* ctx4 = (int4*)out        + (size_t)b * (SEQ / 4);
    int4* tgt4 = (int4*)(out + BS) + (size_t)b * (SEQ / 4);
#pragma unroll
    for (int g = 0; g < 4; ++g) {
        int vidx = g * 256 + tid;
        int p  = vidx * 4;
        int rr = p >> 6;
        int cc = p & 63;
        int m = 0;
#pragma unroll
        for (int j = 0; j < NBLK; ++j) {
            if (rr >= top[j] && rr < bot[j]) {
                int lo = max(lft[j] - cc, 0);
                int hi = min(rgt[j] - cc, 4);
                if (hi > lo) m |= ((1 << (hi - lo)) - 1) << lo;
            }
        }
        int4 tv, cv;
        tv.x =  m       & 1; tv.y = (m >> 1) & 1; tv.z = (m >> 2) & 1; tv.w = (m >> 3) & 1;
        cv.x = tv.x ^ 1;     cv.y = tv.y ^ 1;     cv.z = tv.z ^ 1;     cv.w = tv.w ^ 1;
        tgt4[vidx] = tv;
        ctx4[vidx] = cv;
    }

    // --- swizzled gather + coalesced int4 position stores ---
    __syncthreads();
    int4* pout4 = (int4*)(out + 2 * BS) + (size_t)b * (SEQ / 4);
#pragma unroll
    for (int g = 0; g < 4; ++g) {
        int vidx = g * 256 + tid;
        int i0 = vidx * 4;
        int4 pv;
        pv.x = pos_s[swz(i0 + 0)];
        pv.y = pos_s[swz(i0 + 1)];
        pv.z = pos_s[swz(i0 + 2)];
        pv.w = pos_s[swz(i0 + 3)];
        pout4[vidx] = pv;
    }

    if (tid == 0) out[3 * BS + (size_t)b] = total;
}

extern "C" void kernel_launch(void* const* d_in, const int* in_sizes, int n_in,
                              void* d_out, int out_size, void* d_ws, size_t ws_size,
                              hipStream_t stream) {
    const float* scales     = (const float*)d_in[0];
    const float* rand_tops  = (const float*)d_in[1];
    const float* rand_lefts = (const float*)d_in[2];
    int* out = (int*)d_out;
    int B = in_sizes[0] / NBLK;   // 32768/4 = 8192
    blockmask_kernel<<<B, 256, 0, stream>>>(scales, rand_tops, rand_lefts, out, B);
}

// Round 4
// 403.113 us; speedup vs baseline: 1.0002x; 1.0002x over previous
//
#include <hip/hip_runtime.h>

// BlockMaskGenerator: B=8192, NUM_BLOCKS=4, H=W=64, S=4096.
// Outputs (int32, concatenated): context[B*S], target[B*S], positions[B*S], counts[B].
// positions[b] = stable partition: target indices ascending, then non-target ascending.
//
// Wave-per-row structure (zero __syncthreads):
//  - lane = grid row (64 rows); membership is one uint64 built from <=4 rect intervals.
//  - 64-lane shuffle scan -> target rank; branchless scatter of ushort positions
//    into a wave-private 8 KB LDS slab (wave-synchronous, no barrier).
//  - mask int4 stores take bits from __shfl of the owning lane's uint64 (no recompute).
//  - all global stores are coalesced int4 (1 KB per wave-instruction).

#define NBLK 4
#define HGT 64
#define WID 64
#define SEQ 4096

__global__ __launch_bounds__(256) void blockmask_kernel(
    const float* __restrict__ scales,
    const float* __restrict__ rand_tops,
    const float* __restrict__ rand_lefts,
    int* __restrict__ out,
    int B)
{
    __shared__ unsigned short pos_s[4 * SEQ];   // 32 KB: 8 KB per wave (wave-private)

    const int tid  = threadIdx.x;
    const int lane = tid & 63;
    const int wv   = tid >> 6;
    const int b    = blockIdx.x * 4 + wv;       // one batch row per wave

    // --- build this lane's grid-row membership mask directly from rectangles ---
    unsigned long long mask64 = 0ull;
#pragma unroll
    for (int j = 0; j < NBLK; ++j) {
        int t = b * NBLK + j;
        float sc = scales[t];
        float s = __fadd_rn(0.15f, __fmul_rn(sc, 0.05f));           // no FMA contraction
        int area = (int)__fmul_rn(__fmul_rn(s, 64.0f), 64.0f);      // trunc
        int bh = (int)__fsqrt_rn((float)area);                       // IEEE sqrt, trunc
        bh = min(max(bh, 1), HGT);
        int bw = (int)__fdiv_rn((float)area, (float)bh);             // IEEE div, trunc
        bw = min(max(bw, 1), WID);
        int maxt = max(HGT - bh + 1, 1);
        int maxl = max(WID - bw + 1, 1);
        int tp = (int)__fmul_rn(rand_tops[t],  (float)maxt);
        int lf = (int)__fmul_rn(rand_lefts[t], (float)maxl);
        if (lane >= tp && lane < tp + bh) {
            unsigned long long wm = (bw >= 64) ? ~0ull : ((1ull << bw) - 1ull);
            mask64 |= wm << lf;
        }
    }
    const int cnt = __popcll(mask64);

    // --- 64-lane inclusive shuffle scan (no LDS, no barrier) ---
    int v = cnt;
#pragma unroll
    for (int d = 1; d < 64; d <<= 1) {
        int t = __shfl_up(v, d, 64);
        if (lane >= d) v += t;
    }
    const int total  = __shfl(v, 63, 64);
    const int base_t = v - cnt;                 // targets before this grid row
    const int p0     = lane * 64;
    const int bn0    = total + p0 - base_t;     // non-target dest base for this row

    // --- branchless scatter of the stable partition into wave-private LDS ---
    unsigned short* ps = pos_s + wv * SEQ;
    int pc = 0;
#pragma unroll 16
    for (int k = 0; k < 64; ++k) {
        int bit = (int)((mask64 >> k) & 1ull);
        int idx = bit ? (base_t + pc) : (bn0 + k - pc);
        ps[idx] = (unsigned short)(p0 + k);
        pc += bit;
    }

    // --- coalesced mask stores: bits via 64-bit shuffle of the owning lane ---
    const size_t BS = (size_t)B * SEQ;
    int4* ctx4 = (int4*)out        + (size_t)b * (SEQ / 4);
    int4* tgt4 = (int4*)(out + BS) + (size_t)b * (SEQ / 4);
#pragma unroll
    for (int g = 0; g < 16; ++g) {
        int i = g * 64 + lane;                  // int4 index within the row
        unsigned long long mrow = __shfl(mask64, i >> 4, 64);   // owning grid row
        int nib = (int)((mrow >> ((i & 15) * 4)) & 0xFull);
        int4 tv, cv;
        tv.x =  nib       & 1; tv.y = (nib >> 1) & 1; tv.z = (nib >> 2) & 1; tv.w = (nib >> 3) & 1;
        cv.x = tv.x ^ 1;       cv.y = tv.y ^ 1;       cv.z = tv.z ^ 1;       cv.w = tv.w ^ 1;
        tgt4[i] = tv;
        ctx4[i] = cv;
    }

    // --- wave-synchronous gather + coalesced int4 position stores ---
    __builtin_amdgcn_wave_barrier();            // scheduling fence; lgkmcnt handled by compiler
    int4* pout4 = (int4*)(out + 2 * BS) + (size_t)b * (SEQ / 4);
#pragma unroll
    for (int g = 0; g < 16; ++g) {
        int i = g * 64 + lane;
        const ushort4 u = ((const ushort4*)ps)[i];   // 8B LDS read
        int4 pv;
        pv.x = u.x; pv.y = u.y; pv.z = u.z; pv.w = u.w;
        pout4[i] = pv;
    }

    if (lane == 0) out[3 * BS + (size_t)b] = total;
}

extern "C" void kernel_launch(void* const* d_in, const int* in_sizes, int n_in,
                              void* d_out, int out_size, void* d_ws, size_t ws_size,
                              hipStream_t stream) {
    const float* scales     = (const float*)d_in[0];
    const float* rand_tops  = (const float*)d_in[1];
    const float* rand_lefts = (const float*)d_in[2];
    int* out = (int*)d_out;
    int B = in_sizes[0] / NBLK;   // 32768/4 = 8192
    blockmask_kernel<<<B / 4, 256, 0, stream>>>(scales, rand_tops, rand_lefts, out, B);
}